// Round 4
// baseline (1514.640 us; speedup 1.0000x reference)
//
#include <hip/hip_runtime.h>
#include <math.h>

#define N_NODES 50000
#define N_EDGES 800000
#define HID 64
#define HEADS 4
#define HC 256
#define NEG_SLOPE 0.2f
#define LN_EPS 1e-5f
#define GROUP 8   // edges per group in the fused kernel

__device__ __forceinline__ float bf2f(unsigned short u) {
    return __uint_as_float(((unsigned int)u) << 16);
}
__device__ __forceinline__ unsigned short f2bf(float f) {
    unsigned int u = __float_as_uint(f);
    u = (u + 0x7fffu + ((u >> 16) & 1u)) >> 16;   // RNE
    return (unsigned short)u;
}

// ---------------- K1: xl_bf = bf16(x@W_l+b_l), xr_bf = bf16(x@W_r+b_r) -----
__global__ __launch_bounds__(256) void k_node_transform(
    const float* __restrict__ x,
    const float* __restrict__ W_l, const float* __restrict__ b_l,
    const float* __restrict__ W_r, const float* __restrict__ b_r,
    unsigned short* __restrict__ xl_bf, unsigned short* __restrict__ xr_bf)
{
    __shared__ float xs[8][64];
    const int n0 = blockIdx.x * 8;
    const int t = threadIdx.x;
    for (int i = t; i < 8 * 64; i += 256) xs[i >> 6][i & 63] = x[n0 * 64 + i];
    __syncthreads();

    float accl[8], accr[8];
    const float bl = b_l[t], br = b_r[t];
#pragma unroll
    for (int n = 0; n < 8; n++) { accl[n] = bl; accr[n] = br; }
    for (int k = 0; k < 64; k++) {
        const float wl = W_l[k * 256 + t];
        const float wr = W_r[k * 256 + t];
#pragma unroll
        for (int n = 0; n < 8; n++) {
            accl[n] = fmaf(xs[n][k], wl, accl[n]);
            accr[n] = fmaf(xs[n][k], wr, accr[n]);
        }
    }
#pragma unroll
    for (int n = 0; n < 8; n++) {
        xl_bf[(n0 + n) * 256 + t] = f2bf(accl[n]);
        xr_bf[(n0 + n) * 256 + t] = f2bf(accr[n]);
    }
}

// ---------------- K2: histogram of dst ------------------------------------
__global__ __launch_bounds__(256) void k_hist(const int* __restrict__ ei, int* __restrict__ count)
{
    const int e = blockIdx.x * 256 + threadIdx.x;
    if (e < N_EDGES) atomicAdd(&count[ei[N_EDGES + e]], 1);
}

// ---------------- K3: exclusive scan (single block) ------------------------
__global__ __launch_bounds__(1024) void k_scan(const int* __restrict__ count, int* __restrict__ off)
{
    __shared__ int wsum[16];
    __shared__ int s_carry;
    const int t = threadIdx.x, lane = t & 63, wv = t >> 6;
    if (t == 0) s_carry = 0;
    __syncthreads();
    for (int base = 0; base < N_NODES; base += 8192) {
        const int idx0 = base + t * 8;
        int v[8];
#pragma unroll
        for (int j = 0; j < 8; j++) { int i = idx0 + j; v[j] = (i < N_NODES) ? count[i] : 0; }
#pragma unroll
        for (int j = 1; j < 8; j++) v[j] += v[j - 1];
        const int tot = v[7];
        int sc = tot;
#pragma unroll
        for (int s = 1; s < 64; s <<= 1) { int o = __shfl_up(sc, s, 64); if (lane >= s) sc += o; }
        if (lane == 63) wsum[wv] = sc;
        __syncthreads();
        const int carry = s_carry;
        int woff = 0;
        for (int u = 0; u < wv; u++) woff += wsum[u];
        const int ebase = carry + woff + (sc - tot);
#pragma unroll
        for (int j = 0; j < 8; j++) {
            int i = idx0 + j;
            if (i < N_NODES) off[i] = ebase + (j ? v[j - 1] : 0);
        }
        __syncthreads();
        if (t == 0) { int tt = 0; for (int u = 0; u < 16; u++) tt += wsum[u]; s_carry = carry + tt; }
        __syncthreads();
    }
    if (threadIdx.x == 0) off[N_NODES] = s_carry;
}

// ---------------- K4: scatter src/eid into CSR slots -----------------------
__global__ __launch_bounds__(256) void k_scatter(
    const int* __restrict__ ei, const int* __restrict__ off, int* __restrict__ cursor,
    int* __restrict__ csr_src, int* __restrict__ eid_csr)
{
    const int e = blockIdx.x * 256 + threadIdx.x;
    if (e < N_EDGES) {
        const int s = ei[e];
        const int d = ei[N_EDGES + e];
        const int pos = off[d] + atomicAdd(&cursor[d], 1);
        csr_src[pos] = s;
        eid_csr[pos] = e;
    }
}

// ---------------- K5: FUSED alpha + aggregate + MLP + LN + out-GEMM --------
// 4 waves/block, wave = one node, lane owns channels [lane*4, lane*4+4).
// Per 8-edge group: xl rows loaded ONCE (bf16), used for both the attention
// logit and the weighted aggregation without leaving registers.
__global__ __launch_bounds__(256, 4) void k_fused(
    const int* __restrict__ off, const int* __restrict__ csr_src,
    const int* __restrict__ eid_csr, const float* __restrict__ edge_attr,
    const float* __restrict__ W_e, const float* __restrict__ att,
    const unsigned short* __restrict__ xl_bf, const unsigned short* __restrict__ xr_bf,
    const float* __restrict__ x, const float* __restrict__ bias_gat,
    const float* __restrict__ W1, const float* __restrict__ b1,
    const float* __restrict__ gamma, const float* __restrict__ beta,
    const float* __restrict__ W2, const float* __restrict__ b2,
    float* __restrict__ out)
{
    __shared__ float xs[4][64];
    __shared__ float zs[4][256];
    __shared__ float redS[4][4], redQ[4][4];
    __shared__ float part[4][4][64];

    const int n0 = blockIdx.x * 4;
    const int t = threadIdx.x;
    const int lane = t & 63, wv = t >> 6;
    const int node = n0 + wv;

    for (int i = t; i < 4 * 64; i += 256) xs[i >> 6][i & 63] = x[n0 * 64 + i];

    const float4 att4 = ((const float4*)att)[lane];
    const ushort4 xru = ((const ushort4*)(xr_bf + (size_t)node * 256))[lane];
    const float xr0 = bf2f(xru.x), xr1 = bf2f(xru.y), xr2 = bf2f(xru.z), xr3 = bf2f(xru.w);

    const int mylo = off[node], myhi = off[node + 1];
    float4 g = make_float4(0.f, 0.f, 0.f, 0.f);
    float dsum = 0.f;

    for (int p0 = mylo; p0 < myhi; p0 += GROUP) {
        int eidj[GROUP];
        ushort4 row[GROUP];
        float4 acc[GROUP];
#pragma unroll
        for (int j = 0; j < GROUP; j++) {
            int p = p0 + j; if (p > myhi - 1) p = myhi - 1;   // clamp pads
            const int src = csr_src[p];
            eidj[j] = eid_csr[p];
            row[j] = ((const ushort4*)(xl_bf + (size_t)src * 256))[lane];
        }
#pragma unroll
        for (int j = 0; j < GROUP; j++) {
            acc[j].x = bf2f(row[j].x) + xr0;
            acc[j].y = bf2f(row[j].y) + xr1;
            acc[j].z = bf2f(row[j].z) + xr2;
            acc[j].w = bf2f(row[j].w) + xr3;
        }
        for (int k2 = 0; k2 < 16; k2++) {
            float2 ea[GROUP];
#pragma unroll
            for (int j = 0; j < GROUP; j++)
                ea[j] = *(const float2*)&edge_attr[(size_t)eidj[j] * 32 + k2 * 2];
#pragma unroll
            for (int kk = 0; kk < 2; kk++) {
                const float4 we = ((const float4*)(W_e + (k2 * 2 + kk) * 256))[lane];
#pragma unroll
                for (int j = 0; j < GROUP; j++) {
                    const float e = kk ? ea[j].y : ea[j].x;
                    acc[j].x = fmaf(e, we.x, acc[j].x);
                    acc[j].y = fmaf(e, we.y, acc[j].y);
                    acc[j].z = fmaf(e, we.z, acc[j].z);
                    acc[j].w = fmaf(e, we.w, acc[j].w);
                }
            }
        }
#pragma unroll
        for (int j = 0; j < GROUP; j++) {
            float4 m = acc[j];
            m.x = (m.x > 0.f) ? m.x : NEG_SLOPE * m.x;
            m.y = (m.y > 0.f) ? m.y : NEG_SLOPE * m.y;
            m.z = (m.z > 0.f) ? m.z : NEG_SLOPE * m.z;
            m.w = (m.w > 0.f) ? m.w : NEG_SLOPE * m.w;
            float s = m.x * att4.x + m.y * att4.y + m.z * att4.z + m.w * att4.w;
            s += __shfl_xor(s, 1, 64);
            s += __shfl_xor(s, 2, 64);
            s += __shfl_xor(s, 4, 64);
            s += __shfl_xor(s, 8, 64);   // 16-lane group = one head
            float wexp = __expf(fminf(s, 60.f));
            if (p0 + j >= myhi) wexp = 0.f;   // mask pad slots
            dsum += wexp;
            g.x = fmaf(wexp, bf2f(row[j].x), g.x);
            g.y = fmaf(wexp, bf2f(row[j].y), g.y);
            g.z = fmaf(wexp, bf2f(row[j].z), g.z);
            g.w = fmaf(wexp, bf2f(row[j].w), g.w);
        }
    }
    const float inv = 1.f / (dsum + 1e-16f);
    g.x *= inv; g.y *= inv; g.z *= inv; g.w *= inv;
    ((float4*)zs[wv])[lane] = g;
    __syncthreads();

    // xl1 = tanh(x@W1+b1), channel t, 4 nodes
    float a1[4];
    const float b1v = b1[t];
#pragma unroll
    for (int n = 0; n < 4; n++) a1[n] = b1v;
    for (int k = 0; k < 64; k++) {
        const float w1v = W1[k * 256 + t];
#pragma unroll
        for (int n = 0; n < 4; n++) a1[n] = fmaf(xs[n][k], w1v, a1[n]);
    }

    const float bg = bias_gat[t];
    float z[4];
#pragma unroll
    for (int n = 0; n < 4; n++) z[n] = tanhf(a1[n]) + zs[n][t] + bg;

    // LayerNorm over 256 channels per node
    const float gm = gamma[t], bt = beta[t];
#pragma unroll
    for (int n = 0; n < 4; n++) {
        float s = z[n], q = z[n] * z[n];
#pragma unroll
        for (int m = 1; m < 64; m <<= 1) { s += __shfl_xor(s, m, 64); q += __shfl_xor(q, m, 64); }
        if (lane == 0) { redS[n][wv] = s; redQ[n][wv] = q; }
    }
    __syncthreads();
#pragma unroll
    for (int n = 0; n < 4; n++) {
        const float s = redS[n][0] + redS[n][1] + redS[n][2] + redS[n][3];
        const float q = redQ[n][0] + redQ[n][1] + redQ[n][2] + redQ[n][3];
        const float mu = s * (1.f / 256.f);
        const float var = q * (1.f / 256.f) - mu * mu;
        const float ivn = rsqrtf(var + LN_EPS);
        zs[n][t] = (z[n] - mu) * ivn * gm + bt;
    }
    __syncthreads();

    // out = tanh(z@W2 + b2): thread t -> output col j=t&63, K-chunk q=t>>6
    const int j = t & 63, q = t >> 6;
    float p[4] = {0.f, 0.f, 0.f, 0.f};
    for (int c0 = 0; c0 < 64; c0++) {
        const int c = q * 64 + c0;
        const float w2v = W2[c * 64 + j];
#pragma unroll
        for (int n = 0; n < 4; n++) p[n] = fmaf(zs[n][c], w2v, p[n]);
    }
#pragma unroll
    for (int n = 0; n < 4; n++) part[n][q][j] = p[n];
    __syncthreads();
    {
        const int n = t >> 6, jj = t & 63;
        const float s = part[n][0][jj] + part[n][1][jj] + part[n][2][jj] + part[n][3][jj];
        out[(n0 + n) * 64 + jj] = tanhf(s + b2[jj]);
    }
}

// ---------------- launcher --------------------------------------------------
extern "C" void kernel_launch(void* const* d_in, const int* in_sizes, int n_in,
                              void* d_out, int out_size, void* d_ws, size_t ws_size,
                              hipStream_t stream)
{
    const float* x         = (const float*)d_in[0];
    const int*   ei        = (const int*)d_in[1];
    const float* edge_attr = (const float*)d_in[2];
    const float* W_l       = (const float*)d_in[3];
    const float* b_l       = (const float*)d_in[4];
    const float* W_r       = (const float*)d_in[5];
    const float* b_r       = (const float*)d_in[6];
    const float* W_e       = (const float*)d_in[7];
    const float* att       = (const float*)d_in[8];
    const float* bias_gat  = (const float*)d_in[9];
    const float* W1        = (const float*)d_in[10];
    const float* b1        = (const float*)d_in[11];
    const float* gamma     = (const float*)d_in[12];
    const float* beta      = (const float*)d_in[13];
    const float* W2        = (const float*)d_in[14];
    const float* b2        = (const float*)d_in[15];
    float* out = (float*)d_out;

    char* ws = (char*)d_ws;
    unsigned short* xl_bf = (unsigned short*)ws;  ws += (size_t)N_NODES * HC * 2;  // 25.6 MB
    unsigned short* xr_bf = (unsigned short*)ws;  ws += (size_t)N_NODES * HC * 2;  // 25.6 MB
    int* csr_src          = (int*)ws;             ws += (size_t)N_EDGES * 4;
    int* eid_csr          = (int*)ws;             ws += (size_t)N_EDGES * 4;
    int* count            = (int*)ws;             ws += (size_t)N_NODES * 4;
    int* cursor           = (int*)ws;             ws += (size_t)N_NODES * 4;
    int* off              = (int*)ws;             ws += (size_t)(N_NODES + 1) * 4;

    // zero count + cursor (contiguous)
    hipMemsetAsync(count, 0, 2 * (size_t)N_NODES * sizeof(int), stream);

    k_node_transform<<<N_NODES / 8, 256, 0, stream>>>(x, W_l, b_l, W_r, b_r, xl_bf, xr_bf);
    k_hist<<<(N_EDGES + 255) / 256, 256, 0, stream>>>(ei, count);
    k_scan<<<1, 1024, 0, stream>>>(count, off);
    k_scatter<<<(N_EDGES + 255) / 256, 256, 0, stream>>>(ei, off, cursor, csr_src, eid_csr);
    k_fused<<<N_NODES / 4, 256, 0, stream>>>(off, csr_src, eid_csr, edge_attr, W_e, att,
                                             xl_bf, xr_bf, x, bias_gat,
                                             W1, b1, gamma, beta, W2, b2, out);
}

// Round 5
// 1104.510 us; speedup vs baseline: 1.3713x; 1.3713x over previous
//
#include <hip/hip_runtime.h>
#include <math.h>

#define N_NODES 50000
#define N_EDGES 800000
#define HID 64
#define HEADS 4
#define HC 256
#define NEG_SLOPE 0.2f
#define LN_EPS 1e-5f
#define GROUP 4   // edges per group in the fused kernel (reg-budget-safe)

__device__ __forceinline__ float bf2f(unsigned short u) {
    return __uint_as_float(((unsigned int)u) << 16);
}
__device__ __forceinline__ unsigned short f2bf(float f) {
    unsigned int u = __float_as_uint(f);
    u = (u + 0x7fffu + ((u >> 16) & 1u)) >> 16;   // RNE
    return (unsigned short)u;
}

// ---------------- K1: xl_bf = bf16(x@W_l+b_l), xr_bf = bf16(x@W_r+b_r) -----
__global__ __launch_bounds__(256) void k_node_transform(
    const float* __restrict__ x,
    const float* __restrict__ W_l, const float* __restrict__ b_l,
    const float* __restrict__ W_r, const float* __restrict__ b_r,
    unsigned short* __restrict__ xl_bf, unsigned short* __restrict__ xr_bf)
{
    __shared__ float xs[8][64];
    const int n0 = blockIdx.x * 8;
    const int t = threadIdx.x;
    for (int i = t; i < 8 * 64; i += 256) xs[i >> 6][i & 63] = x[n0 * 64 + i];
    __syncthreads();

    float accl[8], accr[8];
    const float bl = b_l[t], br = b_r[t];
#pragma unroll
    for (int n = 0; n < 8; n++) { accl[n] = bl; accr[n] = br; }
    for (int k = 0; k < 64; k++) {
        const float wl = W_l[k * 256 + t];
        const float wr = W_r[k * 256 + t];
#pragma unroll
        for (int n = 0; n < 8; n++) {
            accl[n] = fmaf(xs[n][k], wl, accl[n]);
            accr[n] = fmaf(xs[n][k], wr, accr[n]);
        }
    }
#pragma unroll
    for (int n = 0; n < 8; n++) {
        xl_bf[(n0 + n) * 256 + t] = f2bf(accl[n]);
        xr_bf[(n0 + n) * 256 + t] = f2bf(accr[n]);
    }
}

// ---------------- K2: histogram of dst ------------------------------------
__global__ __launch_bounds__(256) void k_hist(const int* __restrict__ ei, int* __restrict__ count)
{
    const int e = blockIdx.x * 256 + threadIdx.x;
    if (e < N_EDGES) atomicAdd(&count[ei[N_EDGES + e]], 1);
}

// ---------------- K3: exclusive scan (single block) ------------------------
__global__ __launch_bounds__(1024) void k_scan(const int* __restrict__ count, int* __restrict__ off)
{
    __shared__ int wsum[16];
    __shared__ int s_carry;
    const int t = threadIdx.x, lane = t & 63, wv = t >> 6;
    if (t == 0) s_carry = 0;
    __syncthreads();
    for (int base = 0; base < N_NODES; base += 8192) {
        const int idx0 = base + t * 8;
        int v[8];
#pragma unroll
        for (int j = 0; j < 8; j++) { int i = idx0 + j; v[j] = (i < N_NODES) ? count[i] : 0; }
#pragma unroll
        for (int j = 1; j < 8; j++) v[j] += v[j - 1];
        const int tot = v[7];
        int sc = tot;
#pragma unroll
        for (int s = 1; s < 64; s <<= 1) { int o = __shfl_up(sc, s, 64); if (lane >= s) sc += o; }
        if (lane == 63) wsum[wv] = sc;
        __syncthreads();
        const int carry = s_carry;
        int woff = 0;
        for (int u = 0; u < wv; u++) woff += wsum[u];
        const int ebase = carry + woff + (sc - tot);
#pragma unroll
        for (int j = 0; j < 8; j++) {
            int i = idx0 + j;
            if (i < N_NODES) off[i] = ebase + (j ? v[j - 1] : 0);
        }
        __syncthreads();
        if (t == 0) { int tt = 0; for (int u = 0; u < 16; u++) tt += wsum[u]; s_carry = carry + tt; }
        __syncthreads();
    }
    if (threadIdx.x == 0) off[N_NODES] = s_carry;
}

// ---------------- K4: scatter src/eid into CSR slots -----------------------
__global__ __launch_bounds__(256) void k_scatter(
    const int* __restrict__ ei, const int* __restrict__ off, int* __restrict__ cursor,
    int* __restrict__ csr_src, int* __restrict__ eid_csr)
{
    const int e = blockIdx.x * 256 + threadIdx.x;
    if (e < N_EDGES) {
        const int s = ei[e];
        const int d = ei[N_EDGES + e];
        const int pos = off[d] + atomicAdd(&cursor[d], 1);
        csr_src[pos] = s;
        eid_csr[pos] = e;
    }
}

// ---------------- K5: FUSED alpha + aggregate + MLP + LN + out-GEMM --------
// 4 waves/block, wave = one node, lane owns channels [lane*4, lane*4+4).
// GROUP=4 keeps the live register set ~75 VGPRs -> no scratch spills.
__global__ __launch_bounds__(256) void k_fused(
    const int* __restrict__ off, const int* __restrict__ csr_src,
    const int* __restrict__ eid_csr, const float* __restrict__ edge_attr,
    const float* __restrict__ W_e, const float* __restrict__ att,
    const unsigned short* __restrict__ xl_bf, const unsigned short* __restrict__ xr_bf,
    const float* __restrict__ x, const float* __restrict__ bias_gat,
    const float* __restrict__ W1, const float* __restrict__ b1,
    const float* __restrict__ gamma, const float* __restrict__ beta,
    const float* __restrict__ W2, const float* __restrict__ b2,
    float* __restrict__ out)
{
    __shared__ float xs[4][64];
    __shared__ float zs[4][256];
    __shared__ float redS[4][4], redQ[4][4];
    __shared__ float part[4][4][64];

    const int n0 = blockIdx.x * 4;
    const int t = threadIdx.x;
    const int lane = t & 63, wv = t >> 6;
    const int node = n0 + wv;

    for (int i = t; i < 4 * 64; i += 256) xs[i >> 6][i & 63] = x[n0 * 64 + i];

    const float4 att4 = ((const float4*)att)[lane];
    const ushort4 xru = ((const ushort4*)(xr_bf + (size_t)node * 256))[lane];
    const float xr0 = bf2f(xru.x), xr1 = bf2f(xru.y), xr2 = bf2f(xru.z), xr3 = bf2f(xru.w);

    const int mylo = off[node], myhi = off[node + 1];
    float4 g = make_float4(0.f, 0.f, 0.f, 0.f);
    float dsum = 0.f;

    for (int p0 = mylo; p0 < myhi; p0 += GROUP) {
        int eidj[GROUP];
        ushort4 row[GROUP];
        float4 acc[GROUP];
#pragma unroll
        for (int j = 0; j < GROUP; j++) {
            int p = p0 + j; if (p > myhi - 1) p = myhi - 1;   // clamp pads
            const int src = csr_src[p];
            eidj[j] = __builtin_amdgcn_readfirstlane(eid_csr[p]);  // wave-uniform -> scalar path
            row[j] = ((const ushort4*)(xl_bf + (size_t)src * 256))[lane];
        }
#pragma unroll
        for (int j = 0; j < GROUP; j++) {
            acc[j].x = bf2f(row[j].x) + xr0;
            acc[j].y = bf2f(row[j].y) + xr1;
            acc[j].z = bf2f(row[j].z) + xr2;
            acc[j].w = bf2f(row[j].w) + xr3;
        }
        for (int k2 = 0; k2 < 16; k2++) {
            float2 ea[GROUP];
#pragma unroll
            for (int j = 0; j < GROUP; j++)
                ea[j] = *(const float2*)&edge_attr[(size_t)eidj[j] * 32 + k2 * 2];
#pragma unroll
            for (int kk = 0; kk < 2; kk++) {
                const float4 we = ((const float4*)(W_e + (k2 * 2 + kk) * 256))[lane];
#pragma unroll
                for (int j = 0; j < GROUP; j++) {
                    const float e = kk ? ea[j].y : ea[j].x;
                    acc[j].x = fmaf(e, we.x, acc[j].x);
                    acc[j].y = fmaf(e, we.y, acc[j].y);
                    acc[j].z = fmaf(e, we.z, acc[j].z);
                    acc[j].w = fmaf(e, we.w, acc[j].w);
                }
            }
        }
#pragma unroll
        for (int j = 0; j < GROUP; j++) {
            float4 m = acc[j];
            m.x = (m.x > 0.f) ? m.x : NEG_SLOPE * m.x;
            m.y = (m.y > 0.f) ? m.y : NEG_SLOPE * m.y;
            m.z = (m.z > 0.f) ? m.z : NEG_SLOPE * m.z;
            m.w = (m.w > 0.f) ? m.w : NEG_SLOPE * m.w;
            float s = m.x * att4.x + m.y * att4.y + m.z * att4.z + m.w * att4.w;
            s += __shfl_xor(s, 1, 64);
            s += __shfl_xor(s, 2, 64);
            s += __shfl_xor(s, 4, 64);
            s += __shfl_xor(s, 8, 64);   // 16-lane group = one head
            float wexp = __expf(fminf(s, 60.f));
            if (p0 + j >= myhi) wexp = 0.f;   // mask pad slots
            dsum += wexp;
            g.x = fmaf(wexp, bf2f(row[j].x), g.x);
            g.y = fmaf(wexp, bf2f(row[j].y), g.y);
            g.z = fmaf(wexp, bf2f(row[j].z), g.z);
            g.w = fmaf(wexp, bf2f(row[j].w), g.w);
        }
    }
    const float inv = 1.f / (dsum + 1e-16f);
    g.x *= inv; g.y *= inv; g.z *= inv; g.w *= inv;
    ((float4*)zs[wv])[lane] = g;
    __syncthreads();

    // xl1 = tanh(x@W1+b1), channel t, 4 nodes
    float a1[4];
    const float b1v = b1[t];
#pragma unroll
    for (int n = 0; n < 4; n++) a1[n] = b1v;
    for (int k = 0; k < 64; k++) {
        const float w1v = W1[k * 256 + t];
#pragma unroll
        for (int n = 0; n < 4; n++) a1[n] = fmaf(xs[n][k], w1v, a1[n]);
    }

    const float bg = bias_gat[t];
    float z[4];
#pragma unroll
    for (int n = 0; n < 4; n++) z[n] = tanhf(a1[n]) + zs[n][t] + bg;

    // LayerNorm over 256 channels per node
    const float gm = gamma[t], bt = beta[t];
#pragma unroll
    for (int n = 0; n < 4; n++) {
        float s = z[n], q = z[n] * z[n];
#pragma unroll
        for (int m = 1; m < 64; m <<= 1) { s += __shfl_xor(s, m, 64); q += __shfl_xor(q, m, 64); }
        if (lane == 0) { redS[n][wv] = s; redQ[n][wv] = q; }
    }
    __syncthreads();
#pragma unroll
    for (int n = 0; n < 4; n++) {
        const float s = redS[n][0] + redS[n][1] + redS[n][2] + redS[n][3];
        const float q = redQ[n][0] + redQ[n][1] + redQ[n][2] + redQ[n][3];
        const float mu = s * (1.f / 256.f);
        const float var = q * (1.f / 256.f) - mu * mu;
        const float ivn = rsqrtf(var + LN_EPS);
        zs[n][t] = (z[n] - mu) * ivn * gm + bt;
    }
    __syncthreads();

    // out = tanh(z@W2 + b2): thread t -> output col j=t&63, K-chunk q=t>>6
    const int j = t & 63, q = t >> 6;
    float p[4] = {0.f, 0.f, 0.f, 0.f};
    for (int c0 = 0; c0 < 64; c0++) {
        const int c = q * 64 + c0;
        const float w2v = W2[c * 64 + j];
#pragma unroll
        for (int n = 0; n < 4; n++) p[n] = fmaf(zs[n][c], w2v, p[n]);
    }
#pragma unroll
    for (int n = 0; n < 4; n++) part[n][q][j] = p[n];
    __syncthreads();
    {
        const int n = t >> 6, jj = t & 63;
        const float s = part[n][0][jj] + part[n][1][jj] + part[n][2][jj] + part[n][3][jj];
        out[(n0 + n) * 64 + jj] = tanhf(s + b2[jj]);
    }
}

// ---------------- launcher --------------------------------------------------
extern "C" void kernel_launch(void* const* d_in, const int* in_sizes, int n_in,
                              void* d_out, int out_size, void* d_ws, size_t ws_size,
                              hipStream_t stream)
{
    const float* x         = (const float*)d_in[0];
    const int*   ei        = (const int*)d_in[1];
    const float* edge_attr = (const float*)d_in[2];
    const float* W_l       = (const float*)d_in[3];
    const float* b_l       = (const float*)d_in[4];
    const float* W_r       = (const float*)d_in[5];
    const float* b_r       = (const float*)d_in[6];
    const float* W_e       = (const float*)d_in[7];
    const float* att       = (const float*)d_in[8];
    const float* bias_gat  = (const float*)d_in[9];
    const float* W1        = (const float*)d_in[10];
    const float* b1        = (const float*)d_in[11];
    const float* gamma     = (const float*)d_in[12];
    const float* beta      = (const float*)d_in[13];
    const float* W2        = (const float*)d_in[14];
    const float* b2        = (const float*)d_in[15];
    float* out = (float*)d_out;

    char* ws = (char*)d_ws;
    unsigned short* xl_bf = (unsigned short*)ws;  ws += (size_t)N_NODES * HC * 2;  // 25.6 MB
    unsigned short* xr_bf = (unsigned short*)ws;  ws += (size_t)N_NODES * HC * 2;  // 25.6 MB
    int* csr_src          = (int*)ws;             ws += (size_t)N_EDGES * 4;
    int* eid_csr          = (int*)ws;             ws += (size_t)N_EDGES * 4;
    int* count            = (int*)ws;             ws += (size_t)N_NODES * 4;
    int* cursor           = (int*)ws;             ws += (size_t)N_NODES * 4;
    int* off              = (int*)ws;             ws += (size_t)(N_NODES + 1) * 4;

    // zero count + cursor (contiguous)
    hipMemsetAsync(count, 0, 2 * (size_t)N_NODES * sizeof(int), stream);

    k_node_transform<<<N_NODES / 8, 256, 0, stream>>>(x, W_l, b_l, W_r, b_r, xl_bf, xr_bf);
    k_hist<<<(N_EDGES + 255) / 256, 256, 0, stream>>>(ei, count);
    k_scan<<<1, 1024, 0, stream>>>(count, off);
    k_scatter<<<(N_EDGES + 255) / 256, 256, 0, stream>>>(ei, off, cursor, csr_src, eid_csr);
    k_fused<<<N_NODES / 4, 256, 0, stream>>>(off, csr_src, eid_csr, edge_attr, W_e, att,
                                             xl_bf, xr_bf, x, bias_gat,
                                             W1, b1, gamma, beta, W2, b2, out);
}

// Round 6
// 995.579 us; speedup vs baseline: 1.5214x; 1.1094x over previous
//
#include <hip/hip_runtime.h>
#include <math.h>

#define N_NODES 50000
#define N_EDGES 800000
#define HID 64
#define HEADS 4
#define HC 256
#define NEG_SLOPE 0.2f
#define LN_EPS 1e-5f
#define GROUP 8   // edges per group in the fused kernel

__device__ __forceinline__ float bf2f(unsigned short u) {
    return __uint_as_float(((unsigned int)u) << 16);
}
__device__ __forceinline__ unsigned short f2bf(float f) {
    unsigned int u = __float_as_uint(f);
    u = (u + 0x7fffu + ((u >> 16) & 1u)) >> 16;   // RNE
    return (unsigned short)u;
}

// ---------------- K1: xl_bf = bf16(x@W_l+b_l), xr_bf = bf16(x@W_r+b_r) -----
__global__ __launch_bounds__(256) void k_node_transform(
    const float* __restrict__ x,
    const float* __restrict__ W_l, const float* __restrict__ b_l,
    const float* __restrict__ W_r, const float* __restrict__ b_r,
    unsigned short* __restrict__ xl_bf, unsigned short* __restrict__ xr_bf)
{
    __shared__ float xs[8][64];
    const int n0 = blockIdx.x * 8;
    const int t = threadIdx.x;
    for (int i = t; i < 8 * 64; i += 256) xs[i >> 6][i & 63] = x[n0 * 64 + i];
    __syncthreads();

    float accl[8], accr[8];
    const float bl = b_l[t], br = b_r[t];
#pragma unroll
    for (int n = 0; n < 8; n++) { accl[n] = bl; accr[n] = br; }
    for (int k = 0; k < 64; k++) {
        const float wl = W_l[k * 256 + t];
        const float wr = W_r[k * 256 + t];
#pragma unroll
        for (int n = 0; n < 8; n++) {
            accl[n] = fmaf(xs[n][k], wl, accl[n]);
            accr[n] = fmaf(xs[n][k], wr, accr[n]);
        }
    }
#pragma unroll
    for (int n = 0; n < 8; n++) {
        xl_bf[(n0 + n) * 256 + t] = f2bf(accl[n]);
        xr_bf[(n0 + n) * 256 + t] = f2bf(accr[n]);
    }
}

// ---------------- K2: histogram of dst ------------------------------------
__global__ __launch_bounds__(256) void k_hist(const int* __restrict__ ei, int* __restrict__ count)
{
    const int e = blockIdx.x * 256 + threadIdx.x;
    if (e < N_EDGES) atomicAdd(&count[ei[N_EDGES + e]], 1);
}

// ---------------- K3: exclusive scan (single block) ------------------------
__global__ __launch_bounds__(1024) void k_scan(const int* __restrict__ count, int* __restrict__ off)
{
    __shared__ int wsum[16];
    __shared__ int s_carry;
    const int t = threadIdx.x, lane = t & 63, wv = t >> 6;
    if (t == 0) s_carry = 0;
    __syncthreads();
    for (int base = 0; base < N_NODES; base += 8192) {
        const int idx0 = base + t * 8;
        int v[8];
#pragma unroll
        for (int j = 0; j < 8; j++) { int i = idx0 + j; v[j] = (i < N_NODES) ? count[i] : 0; }
#pragma unroll
        for (int j = 1; j < 8; j++) v[j] += v[j - 1];
        const int tot = v[7];
        int sc = tot;
#pragma unroll
        for (int s = 1; s < 64; s <<= 1) { int o = __shfl_up(sc, s, 64); if (lane >= s) sc += o; }
        if (lane == 63) wsum[wv] = sc;
        __syncthreads();
        const int carry = s_carry;
        int woff = 0;
        for (int u = 0; u < wv; u++) woff += wsum[u];
        const int ebase = carry + woff + (sc - tot);
#pragma unroll
        for (int j = 0; j < 8; j++) {
            int i = idx0 + j;
            if (i < N_NODES) off[i] = ebase + (j ? v[j - 1] : 0);
        }
        __syncthreads();
        if (t == 0) { int tt = 0; for (int u = 0; u < 16; u++) tt += wsum[u]; s_carry = carry + tt; }
        __syncthreads();
    }
    if (threadIdx.x == 0) off[N_NODES] = s_carry;
}

// ---------------- K4: scatter src/eid into CSR slots -----------------------
__global__ __launch_bounds__(256) void k_scatter(
    const int* __restrict__ ei, const int* __restrict__ off, int* __restrict__ cursor,
    int* __restrict__ csr_src, int* __restrict__ eid_csr)
{
    const int e = blockIdx.x * 256 + threadIdx.x;
    if (e < N_EDGES) {
        const int s = ei[e];
        const int d = ei[N_EDGES + e];
        const int pos = off[d] + atomicAdd(&cursor[d], 1);
        csr_src[pos] = s;
        eid_csr[pos] = e;
    }
}

// ---------------- K5: FUSED alpha + aggregate + MLP + LN + out-GEMM --------
// 4 waves/block, wave = one node, lane owns channels [lane*4, lane*4+4).
// Per 8-edge group: edge_attr staged into per-wave LDS via coalesced vector
// loads (no scalar path); xl rows loaded once, used for logit AND aggregation.
__global__ __launch_bounds__(256) void k_fused(
    const int* __restrict__ off, const int* __restrict__ csr_src,
    const int* __restrict__ eid_csr, const float* __restrict__ edge_attr,
    const float* __restrict__ W_e, const float* __restrict__ att,
    const unsigned short* __restrict__ xl_bf, const unsigned short* __restrict__ xr_bf,
    const float* __restrict__ x, const float* __restrict__ bias_gat,
    const float* __restrict__ W1, const float* __restrict__ b1,
    const float* __restrict__ gamma, const float* __restrict__ beta,
    const float* __restrict__ W2, const float* __restrict__ b2,
    float* __restrict__ out)
{
    __shared__ float xs[4][64];
    __shared__ float zs[4][256];
    __shared__ float ea_s[4][GROUP][32];   // per-wave edge_attr staging
    __shared__ float redS[4][4], redQ[4][4];
    __shared__ float part[4][4][64];

    const int n0 = blockIdx.x * 4;
    const int t = threadIdx.x;
    const int lane = t & 63, wv = t >> 6;
    const int node = n0 + wv;

    for (int i = t; i < 4 * 64; i += 256) xs[i >> 6][i & 63] = x[n0 * 64 + i];

    const float4 att4 = ((const float4*)att)[lane];
    const ushort4 xru = ((const ushort4*)(xr_bf + (size_t)node * 256))[lane];
    const float xr0 = bf2f(xru.x), xr1 = bf2f(xru.y), xr2 = bf2f(xru.z), xr3 = bf2f(xru.w);

    const int mylo = off[node], myhi = off[node + 1];
    float4 g = make_float4(0.f, 0.f, 0.f, 0.f);
    float dsum = 0.f;

    for (int p0 = mylo; p0 < myhi; p0 += GROUP) {
        // eids for this group live in lanes 0..GROUP-1
        int eidv = 0;
        {
            int p = p0 + lane; if (p > myhi - 1) p = myhi - 1;
            if (lane < GROUP) eidv = eid_csr[p];
        }
        // stage GROUP x 32 floats of edge_attr into per-wave LDS (coalesced)
#pragma unroll
        for (int i = 0; i < (GROUP * 32) / 64; i++) {
            const int idx = i * 64 + lane;
            const int jj = idx >> 5, kk = idx & 31;
            const int e = __shfl(eidv, jj, 64);
            ea_s[wv][jj][kk] = edge_attr[(size_t)e * 32 + kk];
        }
        // xl row gathers (independent, 8 in flight)
        ushort4 row[GROUP];
#pragma unroll
        for (int j = 0; j < GROUP; j++) {
            int p = p0 + j; if (p > myhi - 1) p = myhi - 1;   // clamp pads
            const int src = csr_src[p];
            row[j] = ((const ushort4*)(xl_bf + (size_t)src * 256))[lane];
        }
        float4 acc[GROUP];
#pragma unroll
        for (int j = 0; j < GROUP; j++) {
            acc[j].x = bf2f(row[j].x) + xr0;
            acc[j].y = bf2f(row[j].y) + xr1;
            acc[j].z = bf2f(row[j].z) + xr2;
            acc[j].w = bf2f(row[j].w) + xr3;
        }
        // W_e transform: k outer (W_e row reused across 8 edges), LDS broadcast ea
        for (int k = 0; k < 32; k++) {
            const float4 we = ((const float4*)(W_e + k * 256))[lane];
#pragma unroll
            for (int j = 0; j < GROUP; j++) {
                const float e = ea_s[wv][j][k];
                acc[j].x = fmaf(e, we.x, acc[j].x);
                acc[j].y = fmaf(e, we.y, acc[j].y);
                acc[j].z = fmaf(e, we.z, acc[j].z);
                acc[j].w = fmaf(e, we.w, acc[j].w);
            }
        }
#pragma unroll
        for (int j = 0; j < GROUP; j++) {
            float4 m = acc[j];
            m.x = (m.x > 0.f) ? m.x : NEG_SLOPE * m.x;
            m.y = (m.y > 0.f) ? m.y : NEG_SLOPE * m.y;
            m.z = (m.z > 0.f) ? m.z : NEG_SLOPE * m.z;
            m.w = (m.w > 0.f) ? m.w : NEG_SLOPE * m.w;
            float s = m.x * att4.x + m.y * att4.y + m.z * att4.z + m.w * att4.w;
            s += __shfl_xor(s, 1, 64);
            s += __shfl_xor(s, 2, 64);
            s += __shfl_xor(s, 4, 64);
            s += __shfl_xor(s, 8, 64);   // 16-lane group = one head
            float wexp = __expf(fminf(s, 60.f));
            if (p0 + j >= myhi) wexp = 0.f;   // mask pad slots
            dsum += wexp;
            g.x = fmaf(wexp, bf2f(row[j].x), g.x);
            g.y = fmaf(wexp, bf2f(row[j].y), g.y);
            g.z = fmaf(wexp, bf2f(row[j].z), g.z);
            g.w = fmaf(wexp, bf2f(row[j].w), g.w);
        }
    }
    const float inv = 1.f / (dsum + 1e-16f);
    g.x *= inv; g.y *= inv; g.z *= inv; g.w *= inv;
    ((float4*)zs[wv])[lane] = g;
    __syncthreads();

    // xl1 = tanh(x@W1+b1), channel t, 4 nodes
    float a1[4];
    const float b1v = b1[t];
#pragma unroll
    for (int n = 0; n < 4; n++) a1[n] = b1v;
    for (int k = 0; k < 64; k++) {
        const float w1v = W1[k * 256 + t];
#pragma unroll
        for (int n = 0; n < 4; n++) a1[n] = fmaf(xs[n][k], w1v, a1[n]);
    }

    const float bg = bias_gat[t];
    float z[4];
#pragma unroll
    for (int n = 0; n < 4; n++) z[n] = tanhf(a1[n]) + zs[n][t] + bg;

    // LayerNorm over 256 channels per node
    const float gm = gamma[t], bt = beta[t];
#pragma unroll
    for (int n = 0; n < 4; n++) {
        float s = z[n], q = z[n] * z[n];
#pragma unroll
        for (int m = 1; m < 64; m <<= 1) { s += __shfl_xor(s, m, 64); q += __shfl_xor(q, m, 64); }
        if (lane == 0) { redS[n][wv] = s; redQ[n][wv] = q; }
    }
    __syncthreads();
#pragma unroll
    for (int n = 0; n < 4; n++) {
        const float s = redS[n][0] + redS[n][1] + redS[n][2] + redS[n][3];
        const float q = redQ[n][0] + redQ[n][1] + redQ[n][2] + redQ[n][3];
        const float mu = s * (1.f / 256.f);
        const float var = q * (1.f / 256.f) - mu * mu;
        const float ivn = rsqrtf(var + LN_EPS);
        zs[n][t] = (z[n] - mu) * ivn * gm + bt;
    }
    __syncthreads();

    // out = tanh(z@W2 + b2): thread t -> output col j=t&63, K-chunk q=t>>6
    const int j = t & 63, q = t >> 6;
    float p[4] = {0.f, 0.f, 0.f, 0.f};
    for (int c0 = 0; c0 < 64; c0++) {
        const int c = q * 64 + c0;
        const float w2v = W2[c * 64 + j];
#pragma unroll
        for (int n = 0; n < 4; n++) p[n] = fmaf(zs[n][c], w2v, p[n]);
    }
#pragma unroll
    for (int n = 0; n < 4; n++) part[n][q][j] = p[n];
    __syncthreads();
    {
        const int n = t >> 6, jj = t & 63;
        const float s = part[n][0][jj] + part[n][1][jj] + part[n][2][jj] + part[n][3][jj];
        out[(n0 + n) * 64 + jj] = tanhf(s + b2[jj]);
    }
}

// ---------------- launcher --------------------------------------------------
extern "C" void kernel_launch(void* const* d_in, const int* in_sizes, int n_in,
                              void* d_out, int out_size, void* d_ws, size_t ws_size,
                              hipStream_t stream)
{
    const float* x         = (const float*)d_in[0];
    const int*   ei        = (const int*)d_in[1];
    const float* edge_attr = (const float*)d_in[2];
    const float* W_l       = (const float*)d_in[3];
    const float* b_l       = (const float*)d_in[4];
    const float* W_r       = (const float*)d_in[5];
    const float* b_r       = (const float*)d_in[6];
    const float* W_e       = (const float*)d_in[7];
    const float* att       = (const float*)d_in[8];
    const float* bias_gat  = (const float*)d_in[9];
    const float* W1        = (const float*)d_in[10];
    const float* b1        = (const float*)d_in[11];
    const float* gamma     = (const float*)d_in[12];
    const float* beta      = (const float*)d_in[13];
    const float* W2        = (const float*)d_in[14];
    const float* b2        = (const float*)d_in[15];
    float* out = (float*)d_out;

    char* ws = (char*)d_ws;
    unsigned short* xl_bf = (unsigned short*)ws;  ws += (size_t)N_NODES * HC * 2;  // 25.6 MB
    unsigned short* xr_bf = (unsigned short*)ws;  ws += (size_t)N_NODES * HC * 2;  // 25.6 MB
    int* csr_src          = (int*)ws;             ws += (size_t)N_EDGES * 4;
    int* eid_csr          = (int*)ws;             ws += (size_t)N_EDGES * 4;
    int* count            = (int*)ws;             ws += (size_t)N_NODES * 4;
    int* cursor           = (int*)ws;             ws += (size_t)N_NODES * 4;
    int* off              = (int*)ws;             ws += (size_t)(N_NODES + 1) * 4;

    // zero count + cursor (contiguous)
    hipMemsetAsync(count, 0, 2 * (size_t)N_NODES * sizeof(int), stream);

    k_node_transform<<<N_NODES / 8, 256, 0, stream>>>(x, W_l, b_l, W_r, b_r, xl_bf, xr_bf);
    k_hist<<<(N_EDGES + 255) / 256, 256, 0, stream>>>(ei, count);
    k_scan<<<1, 1024, 0, stream>>>(count, off);
    k_scatter<<<(N_EDGES + 255) / 256, 256, 0, stream>>>(ei, off, cursor, csr_src, eid_csr);
    k_fused<<<N_NODES / 4, 256, 0, stream>>>(off, csr_src, eid_csr, edge_attr, W_e, att,
                                             xl_bf, xr_bf, x, bias_gat,
                                             W1, b1, gamma, beta, W2, b2, out);
}